// Round 4
// baseline (1130.311 us; speedup 1.0000x reference)
//
#include <hip/hip_runtime.h>

typedef __attribute__((ext_vector_type(8))) short short8;
typedef __attribute__((ext_vector_type(4))) float floatx4;

#define M_TOT 131072   // B*S = 64*2048
#define SEQ   2048
#define NB    8        // n-tiles (1024/128)

__device__ __forceinline__ unsigned bf16rne(float x) {
  unsigned u = __float_as_uint(x);
  return (u + 0x7FFFu + ((u >> 16) & 1u)) >> 16;
}

__device__ __forceinline__ unsigned cvtpk_bf16(float lo, float hi) {
  unsigned r;
  asm("v_cvt_pk_bf16_f32 %0, %1, %2" : "=v"(r) : "v"(lo), "v"(hi));
  return r;
}

#define GLOAD_LDS16(g, l) __builtin_amdgcn_global_load_lds( \
    (const __attribute__((address_space(1))) unsigned int*)(g), \
    (__attribute__((address_space(3))) unsigned int*)(l), 16, 0, 0)

// ---------------------------------------------------------------------------
// Convert W1e fp32 -> bf16 in MFMA-FRAGMENT ORDER.
// Layout: chunk index ((nb*32 + t)*8 + f)*64 + lane  (16B chunks), where
// col d = nb*128 + f*16 + (lane&15), k = t*32 + (lane>>4)*8 + e.
// GEMM stages it with gload_lds (linear dest) -> LDS holds frag order ->
// fragment ds_read_b128 is lane-linear (bank-conflict-free in every phase).
// ---------------------------------------------------------------------------
__global__ __launch_bounds__(128) void convert_w1e_frag_kernel(
    const float* __restrict__ W1, unsigned int* __restrict__ out)
{
  int d = blockIdx.x;        // 0..1023
  int kc = threadIdx.x;      // 0..127 (k = kc*8)
  const float* p = W1 + (size_t)d * 2048 + kc * 8;
  float4 a = *(const float4*)p;
  float4 b = *(const float4*)(p + 4);
  uint4 o;
  o.x = bf16rne(a.x) | (bf16rne(a.y) << 16);
  o.y = bf16rne(a.z) | (bf16rne(a.w) << 16);
  o.z = bf16rne(b.x) | (bf16rne(b.y) << 16);
  o.w = bf16rne(b.z) | (bf16rne(b.w) << 16);
  int nb = d >> 7, f = (d >> 4) & 7, t = kc >> 2;
  int lane = (d & 15) + ((kc & 3) << 4);
  size_t chunk = ((size_t)(nb * 32 + t) * 8 + f) * 64 + lane;
  *(uint4*)(out + chunk * 4) = o;
}

// ---------------------------------------------------------------------------
// Kernel 1: hvec[b,d] = b1[d] + sum_m hid[b,m] * W1[d, 1024+m]
// ---------------------------------------------------------------------------
__global__ __launch_bounds__(256) void hvec_kernel(
    const float* __restrict__ hid, const float* __restrict__ W1,
    const float* __restrict__ b1, float* __restrict__ hvec)
{
  int b = blockIdx.x, g = blockIdx.y;
  int w = threadIdx.x >> 6, lane = threadIdx.x & 63;
  const float* hrow = hid + b * 1024;
  for (int i = 0; i < 4; ++i) {
    int d = g * 16 + w * 4 + i;
    const float* wrow = W1 + (size_t)d * 2048 + 1024;
    float sum = 0.f;
#pragma unroll
    for (int c = 0; c < 4; ++c) {
      int m = c * 256 + lane * 4;
      float4 wv = *(const float4*)(wrow + m);
      float4 hv = *(const float4*)(hrow + m);
      sum += wv.x * hv.x + wv.y * hv.y + wv.z * hv.z + wv.w * hv.w;
    }
#pragma unroll
    for (int msk = 1; msk < 64; msk <<= 1) sum += __shfl_xor(sum, msk);
    if (lane == 0) hvec[b * 1024 + d] = sum + b1[d];
  }
}

// ---------------------------------------------------------------------------
// Kernel 2 (primary): 128x128 tile, BK=32, 256 thr (4 waves 2x2), 3 blocks/CU.
// - A staged from fp32 enc via registers + v_cvt_pk_bf16_f32 into frag-order
//   LDS (convert_enc kernel ELIMINATED). Issue-early/write-late (T14).
// - B staged via gload_lds from pre-swizzled frag-order W1eB (linear dest).
// - Frag reads lane-linear -> conflict-free. 1 raw barrier + vmcnt(6)/K-step.
// - A dbuf x2 (8KB each), B ring x4 (8KB each): writes always >=2 barriers
//   from last readers. LDS 48KB/block -> 3 blocks/CU co-resident (overlap).
// Pipeline (iter t): ds_write A(t)[regs] | load aReg(t+1) | gload B(t+1)
//   | vmcnt(6) (drains B(t); aReg(t+1)+B(t+1)=6 stay in flight)
//   | lgkmcnt(0) | s_barrier | 8 ds_read + 16 MFMA.
// ---------------------------------------------------------------------------
__global__ __launch_bounds__(256, 3) void gemm128_kernel(
    const float* __restrict__ enc, const unsigned short* __restrict__ Bfrag,
    const float* __restrict__ W2, const float* __restrict__ hvec,
    float* __restrict__ epart)
{
  __shared__ __align__(16) unsigned short ldsA[2][4096];   // 16 KB
  __shared__ __align__(16) unsigned short ldsB[4][4096];   // 32 KB

  const int tid = threadIdx.x;
  const int lid = blockIdx.x;            // 0..8191
  const int xcd = lid & 7, q = lid >> 3; // bijective XCD swizzle (8192%8==0)
  const int mb = xcd * 128 + (q >> 3);   // 0..1023
  const int nb = q & 7;                  // 0..7
  const int r0 = mb * 128;
  const int bidx = mb >> 4;              // batch (128 divides S=2048)
  const int wid = tid >> 6, lane = tid & 63;
  const int wm = wid >> 1, wn = wid & 1;
  const int lrow = lane & 15, kq = lane >> 4;

  // A staging map: chunk c = tid + j*256 -> row = c>>2, kc = c&3
  const float* aSrc[2];
  int aDst[2];
#pragma unroll
  for (int j = 0; j < 2; ++j) {
    int c = tid + j * 256, row = c >> 2, kc = c & 3;
    aSrc[j] = enc + (size_t)(r0 + row) * 1024 + kc * 8;
    aDst[j] = ((row >> 4) * 64 + (row & 15) + (kc << 4)) * 8;  // shorts
  }
  const unsigned short* bBase = Bfrag + (size_t)nb * 32 * 4096;

  floatx4 acc[4][4];
#pragma unroll
  for (int i = 0; i < 4; ++i)
#pragma unroll
    for (int j = 0; j < 4; ++j)
      acc[i][j] = (floatx4){0.f, 0.f, 0.f, 0.f};

  // prologue: aReg(0) + B(0) in flight
  float4 aR[2][2];
#pragma unroll
  for (int j = 0; j < 2; ++j) {
    aR[j][0] = *(const float4*)(aSrc[j]);
    aR[j][1] = *(const float4*)(aSrc[j] + 4);
  }
  GLOAD_LDS16(bBase + tid * 8,         &ldsB[0][wid * 512]);
  GLOAD_LDS16(bBase + (tid + 256) * 8, &ldsB[0][wid * 512 + 2048]);

  const int aOff = wm * 2048 + lane * 8;   // + mt*512
  const int bOff = wn * 2048 + lane * 8;   // + nt*512

  for (int tt = 0; tt < 8; ++tt) {
#pragma unroll
    for (int u = 0; u < 4; ++u) {
      const int t = tt * 4 + u;
      const int sA = u & 1;                // (tt*4+u)&1
      const int sB = u;                    // (tt*4+u)&3
      const int sBn = (u + 1) & 3;
      // 1) commit A(t) regs -> frag-order LDS
#pragma unroll
      for (int j = 0; j < 2; ++j) {
        uint4 o;
        o.x = cvtpk_bf16(aR[j][0].x, aR[j][0].y);
        o.y = cvtpk_bf16(aR[j][0].z, aR[j][0].w);
        o.z = cvtpk_bf16(aR[j][1].x, aR[j][1].y);
        o.w = cvtpk_bf16(aR[j][1].z, aR[j][1].w);
        *(uint4*)&ldsA[sA][aDst[j]] = o;
      }
      const bool more = (u < 3) || (tt < 7);   // t < 31
      if (more) {
        // 2) issue aReg(t+1)
#pragma unroll
        for (int j = 0; j < 2; ++j) {
          aR[j][0] = *(const float4*)(aSrc[j] + (t + 1) * 32);
          aR[j][1] = *(const float4*)(aSrc[j] + (t + 1) * 32 + 4);
        }
        // 3) issue B(t+1) DMA into ring slot (readers were at t-3)
        GLOAD_LDS16(bBase + (size_t)(t + 1) * 4096 + tid * 8,
                    &ldsB[sBn][wid * 512]);
        GLOAD_LDS16(bBase + (size_t)(t + 1) * 4096 + (tid + 256) * 8,
                    &ldsB[sBn][wid * 512 + 2048]);
        asm volatile("s_waitcnt vmcnt(6)" ::: "memory");  // B(t) landed
      } else {
        asm volatile("s_waitcnt vmcnt(0)" ::: "memory");
      }
      asm volatile("s_waitcnt lgkmcnt(0)" ::: "memory");   // A(t) writes done
      __builtin_amdgcn_s_barrier();                        // publish A(t),B(t)
      // 4) compute: lane-linear frag reads (conflict-free) + 16 MFMA
      short8 af[4], bf[4];
#pragma unroll
      for (int mt = 0; mt < 4; ++mt)
        af[mt] = *(const short8*)&ldsA[sA][aOff + mt * 512];
#pragma unroll
      for (int nt = 0; nt < 4; ++nt)
        bf[nt] = *(const short8*)&ldsB[sB][bOff + nt * 512];
      __builtin_amdgcn_s_setprio(1);
#pragma unroll
      for (int mt = 0; mt < 4; ++mt)
#pragma unroll
        for (int nt = 0; nt < 4; ++nt)
          acc[mt][nt] = __builtin_amdgcn_mfma_f32_16x16x32_bf16(
              af[mt], bf[nt], acc[mt][nt], 0, 0, 0);
      __builtin_amdgcn_s_setprio(0);
    }
  }

  // epilogue: tanh + W2-dot -> epart plane nb
  __syncthreads();
  float* ep = (float*)&ldsA[0][0];   // [2 wn][128 m]
  float hv[4], w2v[4];
#pragma unroll
  for (int nt = 0; nt < 4; ++nt) {
    int n = nb * 128 + wn * 64 + nt * 16 + lrow;
    hv[nt]  = hvec[bidx * 1024 + n];
    w2v[nt] = W2[n];
  }
#pragma unroll
  for (int mt = 0; mt < 4; ++mt) {
#pragma unroll
    for (int r = 0; r < 4; ++r) {
      float sum = 0.f;
#pragma unroll
      for (int nt = 0; nt < 4; ++nt) {
        float pre = acc[mt][nt][r] + hv[nt];
        float ex = __expf(2.f * pre);
        sum += (1.f - 2.f / (ex + 1.f)) * w2v[nt];
      }
      sum += __shfl_xor(sum, 1);
      sum += __shfl_xor(sum, 2);
      sum += __shfl_xor(sum, 4);
      sum += __shfl_xor(sum, 8);
      if (lrow == 0) ep[wn * 128 + wm * 64 + mt * 16 + kq * 4 + r] = sum;
    }
  }
  __syncthreads();
  if (tid < 128)
    epart[(size_t)nb * M_TOT + r0 + tid] = ep[tid] + ep[128 + tid];
}

// ---------------------------------------------------------------------------
// Kernel 2 (fallback, no-ws path): fused GEMM with in-loop convert (128-tile).
// ---------------------------------------------------------------------------
__global__ __launch_bounds__(256) void fused_gemm_kernel(
    const float* __restrict__ enc, const float* __restrict__ W1,
    const float* __restrict__ W2, const float* __restrict__ hvec,
    float* __restrict__ epart)
{
  __shared__ __align__(16) unsigned short Ah[128 * 32];
  __shared__ __align__(16) unsigned short Bh[128 * 32];
  __shared__ float ep[2][128];

  const int tid = threadIdx.x;
  const int nb = blockIdx.x, mb = blockIdx.y;
  const int r0 = mb * 128, n0 = nb * 128;
  const int bidx = r0 >> 11;
  const int w = tid >> 6, lane = tid & 63;
  const int wm = w >> 1, wn = w & 1;
  const int lrow = lane & 15, kq = lane >> 4;

  floatx4 acc[4][4];
#pragma unroll
  for (int i = 0; i < 4; ++i)
#pragma unroll
    for (int j = 0; j < 4; ++j)
      acc[i][j] = (floatx4){0.f, 0.f, 0.f, 0.f};

  const int srow = tid >> 3;
  const int scol = (tid & 7) * 4;
  const float* aptr = enc + (size_t)(r0 + srow) * 1024 + scol;
  const float* bptr = W1  + (size_t)(n0 + srow) * 2048 + scol;

  for (int k0 = 0; k0 < 1024; k0 += 32) {
    float4 av[4], bv[4];
#pragma unroll
    for (int j = 0; j < 4; ++j) {
      av[j] = *(const float4*)(aptr + (size_t)(j * 32) * 1024 + k0);
      bv[j] = *(const float4*)(bptr + (size_t)(j * 32) * 2048 + k0);
    }
    __syncthreads();
#pragma unroll
    for (int j = 0; j < 4; ++j) {
      unsigned ax = __float_as_uint(av[j].x), ay = __float_as_uint(av[j].y);
      unsigned az = __float_as_uint(av[j].z), aw = __float_as_uint(av[j].w);
      unsigned a01 = __builtin_amdgcn_perm(ay, ax, 0x07060302u);
      unsigned a23 = __builtin_amdgcn_perm(aw, az, 0x07060302u);
      *(uint2*)&Ah[(tid + j * 256) * 4] = make_uint2(a01, a23);
      unsigned bx = __float_as_uint(bv[j].x), by = __float_as_uint(bv[j].y);
      unsigned bz = __float_as_uint(bv[j].z), bw = __float_as_uint(bv[j].w);
      unsigned b01 = __builtin_amdgcn_perm(by, bx, 0x07060302u);
      unsigned b23 = __builtin_amdgcn_perm(bw, bz, 0x07060302u);
      *(uint2*)&Bh[(tid + j * 256) * 4] = make_uint2(b01, b23);
    }
    __syncthreads();

    short8 af[4], bfm[4];
#pragma unroll
    for (int t4 = 0; t4 < 4; ++t4) {
      af[t4]  = *(const short8*)&Ah[(wm * 64 + t4 * 16 + lrow) * 32 + kq * 8];
      bfm[t4] = *(const short8*)&Bh[(wn * 64 + t4 * 16 + lrow) * 32 + kq * 8];
    }
#pragma unroll
    for (int mt = 0; mt < 4; ++mt)
#pragma unroll
      for (int nt = 0; nt < 4; ++nt)
        acc[mt][nt] = __builtin_amdgcn_mfma_f32_16x16x32_bf16(
            af[mt], bfm[nt], acc[mt][nt], 0, 0, 0);
  }

  float hv[4], w2v[4];
#pragma unroll
  for (int nt = 0; nt < 4; ++nt) {
    int n = n0 + wn * 64 + nt * 16 + lrow;
    hv[nt]  = hvec[bidx * 1024 + n];
    w2v[nt] = W2[n];
  }
#pragma unroll
  for (int mt = 0; mt < 4; ++mt) {
#pragma unroll
    for (int r = 0; r < 4; ++r) {
      float sum = 0.f;
#pragma unroll
      for (int nt = 0; nt < 4; ++nt) {
        float pre = acc[mt][nt][r] + hv[nt];
        float ex = __expf(2.f * pre);
        sum += (1.f - 2.f / (ex + 1.f)) * w2v[nt];
      }
      sum += __shfl_xor(sum, 1);
      sum += __shfl_xor(sum, 2);
      sum += __shfl_xor(sum, 4);
      sum += __shfl_xor(sum, 8);
      if (lrow == 0) ep[wn][wm * 64 + mt * 16 + kq * 4 + r] = sum;
    }
  }
  __syncthreads();
  if (tid < 128)
    epart[(size_t)nb * M_TOT + r0 + tid] = ep[0][tid] + ep[1][tid];
}

// ---------------------------------------------------------------------------
// Kernel 3: softmax over S per batch (8 epart planes).
// ---------------------------------------------------------------------------
__global__ __launch_bounds__(256) void softmax_kernel(
    const float* __restrict__ epart, float* __restrict__ alpha)
{
  int b = blockIdx.x, t = threadIdx.x;
  __shared__ float redmax[4], redsum[4];
  float ev[8];
  float lmax = -1e30f;
#pragma unroll
  for (int j = 0; j < 8; ++j) {
    int s = t + j * 256;
    float sum = 0.f;
#pragma unroll
    for (int p = 0; p < 8; ++p) sum += epart[(size_t)p * M_TOT + b * SEQ + s];
    ev[j] = sum;
    lmax = fmaxf(lmax, sum);
  }
#pragma unroll
  for (int msk = 1; msk < 64; msk <<= 1) lmax = fmaxf(lmax, __shfl_xor(lmax, msk));
  if ((t & 63) == 0) redmax[t >> 6] = lmax;
  __syncthreads();
  float bmax = fmaxf(fmaxf(redmax[0], redmax[1]), fmaxf(redmax[2], redmax[3]));
  float lsum = 0.f;
#pragma unroll
  for (int j = 0; j < 8; ++j) { ev[j] = __expf(ev[j] - bmax); lsum += ev[j]; }
#pragma unroll
  for (int msk = 1; msk < 64; msk <<= 1) lsum += __shfl_xor(lsum, msk);
  if ((t & 63) == 0) redsum[t >> 6] = lsum;
  __syncthreads();
  float inv = 1.f / (redsum[0] + redsum[1] + redsum[2] + redsum[3]);
#pragma unroll
  for (int j = 0; j < 8; ++j) alpha[b * SEQ + t + j * 256] = ev[j] * inv;
}

// ---------------------------------------------------------------------------
// Kernel 4 (primary): context from fp32 enc, atomic-free. grid (64,8) x 512.
// ---------------------------------------------------------------------------
__global__ __launch_bounds__(512) void context_f32_kernel(
    const float* __restrict__ enc, const float* __restrict__ alpha,
    float* __restrict__ out)
{
  __shared__ float red[16][128];
  int b = blockIdx.x, kc = blockIdx.y, t = threadIdx.x;
  int kl = (t & 31) * 4;              // k-local 0..124
  int strip = t >> 5;                 // 0..15
  const float* ep = enc + ((size_t)b * SEQ + strip * 128) * 1024 + kc * 128 + kl;
  const float* ap = alpha + b * SEQ + strip * 128;
  float a0 = 0.f, a1 = 0.f, a2 = 0.f, a3 = 0.f;
#pragma unroll 4
  for (int s = 0; s < 128; ++s) {
    float a = ap[s];
    float4 v = *(const float4*)(ep + (size_t)s * 1024);
    a0 += a * v.x; a1 += a * v.y; a2 += a * v.z; a3 += a * v.w;
  }
  red[strip][kl + 0] = a0;
  red[strip][kl + 1] = a1;
  red[strip][kl + 2] = a2;
  red[strip][kl + 3] = a3;
  __syncthreads();
  if (t < 128) {
    float s = 0.f;
#pragma unroll
    for (int j = 0; j < 16; ++j) s += red[j][t];
    out[b * 1024 + kc * 128 + t] = s;
  }
}

// ---------------------------------------------------------------------------
// Kernel 4 (fallback): fp32 context with atomics.
// ---------------------------------------------------------------------------
__global__ __launch_bounds__(256) void context_kernel(
    const float* __restrict__ enc, const float* __restrict__ alpha,
    float* __restrict__ out)
{
  int b = blockIdx.y, sq = blockIdx.z, t = threadIdx.x;
  int k4 = t * 4;
  const float* ep = enc + ((size_t)b * SEQ + sq * 128) * 1024 + k4;
  const float* ap = alpha + b * SEQ + sq * 128;
  float ax = 0.f, ay = 0.f, az = 0.f, aw = 0.f;
#pragma unroll 4
  for (int s = 0; s < 128; ++s) {
    float a = ap[s];
    float4 v = *(const float4*)(ep + (size_t)s * 1024);
    ax += a * v.x; ay += a * v.y; az += a * v.z; aw += a * v.w;
  }
  float* o = out + b * 1024 + k4;
  atomicAdd(o + 0, ax);
  atomicAdd(o + 1, ay);
  atomicAdd(o + 2, az);
  atomicAdd(o + 3, aw);
}

// ---------------------------------------------------------------------------
extern "C" void kernel_launch(void* const* d_in, const int* in_sizes, int n_in,
                              void* d_out, int out_size, void* d_ws, size_t ws_size,
                              hipStream_t stream) {
  const float* hid = (const float*)d_in[0];
  const float* enc = (const float*)d_in[1];
  const float* W1  = (const float*)d_in[2];
  const float* b1  = (const float*)d_in[3];
  const float* W2  = (const float*)d_in[4];
  float* out = (float*)d_out;

  float* epart = (float*)d_ws;                       // NB * M_TOT planes
  float* alpha = epart + (size_t)NB * M_TOT;         // M_TOT
  float* hvec  = alpha + M_TOT;                      // 64*1024
  size_t small_bytes = ((size_t)NB * M_TOT + M_TOT + 64 * 1024) * 4;
  size_t w1eb_off = ((small_bytes + 255) / 256) * 256;
  size_t need = w1eb_off + (size_t)1024 * 1024 * 2;  // frag-order W1eB only

  hvec_kernel<<<dim3(64, 64), 256, 0, stream>>>(hid, W1, b1, hvec);

  if (ws_size >= need) {
    unsigned short* W1eB = (unsigned short*)((char*)d_ws + w1eb_off);
    convert_w1e_frag_kernel<<<1024, 128, 0, stream>>>(W1, (unsigned int*)W1eB);
    gemm128_kernel<<<8192, 256, 0, stream>>>(enc, W1eB, W2, hvec, epart);
    softmax_kernel<<<64, 256, 0, stream>>>(epart, alpha);
    context_f32_kernel<<<dim3(64, 8), 512, 0, stream>>>(enc, alpha, out);
  } else {
    hipMemsetAsync(d_out, 0, (size_t)out_size * sizeof(float), stream);
    fused_gemm_kernel<<<dim3(NB, 1024), 256, 0, stream>>>(enc, W1, W2, hvec, epart);
    softmax_kernel<<<64, 256, 0, stream>>>(epart, alpha);
    context_kernel<<<dim3(1, 64, 16), 256, 0, stream>>>(enc, alpha, out);
  }
}